// Round 14
// baseline (526.861 us; speedup 1.0000x reference)
//
#include <hip/hip_runtime.h>

#define N_NODES 8192
#define CAP 128    // neighbor capacity; Binomial(8192,1/256): P(deg>128) ~ 0
constexpr int AST = 132;  // activation LDS row stride: 16B-aligned, +4 pad

typedef unsigned u32x4 __attribute__((ext_vector_type(4)));

// ---------------------------------------------------------------------------
// Kernel 1: adj scan -> CSR. One row per wave, zero barriers, chunk-level
// double buffer, nontemporal loads. Proven <= 61us (R10/R11 reps probes).
// ---------------------------------------------------------------------------
__global__ __launch_bounds__(256, 4) void scan_kernel(
    const float* __restrict__ adj, int* __restrict__ cnt,
    int* __restrict__ nbr) {
  const int t = threadIdx.x;
  const int lane = t & 63;
  const int row = blockIdx.x * 4 + (t >> 6);
  const u32x4* rowp = (const u32x4*)(adj + (size_t)row * N_NODES);
  int* nbr_row = nbr + (size_t)row * CAP;
  u32x4 v[8], vn[8];
#pragma unroll
  for (int i = 0; i < 8; ++i) v[i] = __builtin_nontemporal_load(&rowp[i * 64 + lane]);
  int running = 0;
  for (int ch = 0; ch < 4; ++ch) {
    if (ch < 3) {
      const u32x4* cp = rowp + (ch + 1) * 512;
#pragma unroll
      for (int i = 0; i < 8; ++i) vn[i] = __builtin_nontemporal_load(&cp[i * 64 + lane]);
    }
    int c = 0;
#pragma unroll
    for (int i = 0; i < 8; ++i)
      c += (v[i].x != 0u) + (v[i].y != 0u) + (v[i].z != 0u) + (v[i].w != 0u);
    int incl = c;
#pragma unroll
    for (int s = 1; s < 64; s <<= 1) {
      int n = __shfl_up(incl, s);
      if (lane >= s) incl += n;
    }
    int off = running + incl - c;
    running += __shfl(incl, 63);
    const int colbase = ch * 2048;
#pragma unroll
    for (int i = 0; i < 8; ++i) {
      if (v[i].x | v[i].y | v[i].z | v[i].w) {
        const int col = colbase + (i * 64 + lane) * 4;
        if (v[i].x) { if (off < CAP) nbr_row[off] = col + 0; ++off; }
        if (v[i].y) { if (off < CAP) nbr_row[off] = col + 1; ++off; }
        if (v[i].z) { if (off < CAP) nbr_row[off] = col + 2; ++off; }
        if (v[i].w) { if (off < CAP) nbr_row[off] = col + 3; ++off; }
      }
    }
#pragma unroll
    for (int i = 0; i < 8; ++i) v[i] = vn[i];
  }
  if (lane == 0) cnt[row] = running;
}

// ---------------------------------------------------------------------------
// Barrier-free 2D-register-tiled MLP layer: W read DIRECTLY from global
// (L1/L2-broadcast; every block walks the same addresses) -> no W staging,
// no per-chunk __syncthreads; the kg loop is a pure pipelined stream.
// Caller places ONE __syncthreads between layers.
// SCALEMODE: 0 none, 1 rowscale[node] (mask), 2 rsqrt(cnt[node]+1) (dinv).
// ---------------------------------------------------------------------------
template <int MT, int K, int KSPLIT, int F, bool RELU, bool BIAS, int SCALEMODE>
__device__ __forceinline__ void layer_g(
    const float (*__restrict__ A0)[AST], const float (*__restrict__ A1)[AST],
    float (*__restrict__ Aout)[AST],
    const float* __restrict__ W, const float* __restrict__ bias,
    float* __restrict__ gout, const float* __restrict__ rowscale,
    const int* __restrict__ degcnt, int n0, int t) {
  constexpr int WC = (F >= 128) ? 2 : 1;  // col-waves
  constexpr int WR = 4 / WC;              // row-waves
  constexpr int TC = F / WC / 16;         // cols per lane (=4)
  constexpr int TR = MT / WR / 4;         // rows per lane
  const int w = t >> 6, lane = t & 63;
  const int wc = w % WC, wr = w / WC;
  const int cg = lane & 15, rg = lane >> 4;
  const int c0 = wc * (F / WC) + cg * TC;
  const int r0 = wr * (MT / WR) + rg * TR;
  float acc[TR][TC] = {};

#pragma unroll 4
  for (int kg = 0; kg < K / 4; ++kg) {
    const int k = kg * 4;
    const float (*__restrict__ As)[AST] = (k < KSPLIT) ? A0 : A1;
    const int kk = (k < KSPLIT) ? k : k - KSPLIT;
    float4 a[TR];
#pragma unroll
    for (int i = 0; i < TR; ++i) a[i] = *(const float4*)&As[r0 + i][kk];
    float4 wv[TC];
#pragma unroll
    for (int j = 0; j < TC; ++j)
      wv[j] = *(const float4*)&W[(size_t)(c0 + j) * K + k];
#pragma unroll
    for (int i = 0; i < TR; ++i) {
#pragma unroll
      for (int j = 0; j < TC; ++j) {
        float s = acc[i][j];
        s = fmaf(a[i].x, wv[j].x, s);
        s = fmaf(a[i].y, wv[j].y, s);
        s = fmaf(a[i].z, wv[j].z, s);
        s = fmaf(a[i].w, wv[j].w, s);
        acc[i][j] = s;
      }
    }
  }
  float bvals[TC];
#pragma unroll
  for (int j = 0; j < TC; ++j) bvals[j] = BIAS ? bias[c0 + j] : 0.f;
#pragma unroll
  for (int i = 0; i < TR; ++i) {
    const int node = n0 + r0 + i;
    float scale = 1.f;
    if (SCALEMODE == 1) scale = rowscale[node];
    if (SCALEMODE == 2) scale = rsqrtf((float)degcnt[node] + 1.0f);
    float4 o;
    float* op = (float*)&o;
#pragma unroll
    for (int j = 0; j < TC; ++j) {
      float v = acc[i][j];
      if (BIAS) v += bvals[j];
      if (RELU) v = fmaxf(v, 0.f);
      if (SCALEMODE) v *= scale;
      op[j] = v;
    }
    if (Aout) *(float4*)&Aout[r0 + i][c0] = o;
    if (gout) *(float4*)&gout[(size_t)node * F + c0] = o;
  }
}

// ---------------------------------------------------------------------------
// Kernel 2: encoder x -> h1 -> h ; msg = (h @ wg.T) * dinv  (256 blocks, MT=32)
// 3 barriers total.
// ---------------------------------------------------------------------------
__global__ __launch_bounds__(256) void encode_kernel(
    const float* __restrict__ x,
    const float* __restrict__ w1, const float* __restrict__ b1,
    const float* __restrict__ w2, const float* __restrict__ b2,
    const float* __restrict__ wg, const int* __restrict__ cnt,
    float* __restrict__ h_out, float* __restrict__ msg_out) {
  __shared__ float bufA[32][AST];
  __shared__ float bufB[32][AST];
  const int t = threadIdx.x;
  const int n0 = blockIdx.x * 32;
  {  // stage x tile: 32x32 floats = 256 float4
    int row = t >> 3, k4 = (t & 7) * 4;
    *(float4*)&bufA[row][k4] = *(const float4*)&x[(size_t)(n0 + row) * 32 + k4];
  }
  __syncthreads();
  layer_g<32, 32, 32, 64, true, true, 0>(bufA, nullptr, bufB, w1, b1, nullptr, nullptr, nullptr, n0, t);
  __syncthreads();
  layer_g<32, 64, 64, 128, true, true, 0>(bufB, nullptr, bufA, w2, b2, h_out, nullptr, nullptr, n0, t);
  __syncthreads();
  layer_g<32, 128, 128, 128, false, false, 2>(bufA, nullptr, nullptr, wg, nullptr, msg_out, nullptr, cnt, n0, t);
}

// ---------------------------------------------------------------------------
// Kernel 3: agg (R9 structure, unchanged — ~19us within measured enc+agg=41).
// ---------------------------------------------------------------------------
__global__ __launch_bounds__(256) void agg_kernel(
    const int* __restrict__ cnt, const int* __restrict__ nbr,
    const float* __restrict__ msg, const float* __restrict__ bg,
    const float* __restrict__ adj, float* __restrict__ g1) {
  const int t = threadIdx.x;
  const int f = t & 127;
  const int rA = blockIdx.x * 4 + (t >> 7) * 2;
  const int rB = rA + 1;
  const int cA = cnt[rA], cB = cnt[rB];
  float a0 = msg[(size_t)rA * 128 + f];
  float a1 = msg[(size_t)rB * 128 + f];
  if (cA <= CAP && cB <= CAP) {
    const int* nA = nbr + (size_t)rA * CAP;
    const int* nB = nbr + (size_t)rB * CAP;
    const int cm = max(cA, cB);
    for (int i = 0; i < cm; i += 4) {
#pragma unroll
      for (int k = 0; k < 4; ++k) {
        const int ii = i + k;
        int jA = nA[ii < cA ? ii : 0] & (N_NODES - 1);
        int jB = nB[ii < cB ? ii : 0] & (N_NODES - 1);
        float vA = msg[(size_t)jA * 128 + f];
        float vB = msg[(size_t)jB * 128 + f];
        a0 += (ii < cA) ? vA : 0.f;
        a1 += (ii < cB) ? vB : 0.f;
      }
    }
  } else {
    a0 = msg[(size_t)rA * 128 + f];
    a1 = msg[(size_t)rB * 128 + f];
    for (int col = 0; col < N_NODES; ++col) {
      if (adj[(size_t)rA * N_NODES + col] != 0.f) a0 += msg[(size_t)col * 128 + f];
      if (adj[(size_t)rB * N_NODES + col] != 0.f) a1 += msg[(size_t)col * 128 + f];
    }
  }
  float o0 = fmaf(rsqrtf((float)cA + 1.0f), a0, bg[f]);
  float o1 = fmaf(rsqrtf((float)cB + 1.0f), a1, bg[f]);
  g1[(size_t)rA * 128 + f] = fmaxf(o0, 0.f);
  g1[(size_t)rB * 128 + f] = fmaxf(o1, 0.f);
}

// ---------------------------------------------------------------------------
// Kernel 4: decoder g1 -> g2 -> p1([g2|h]) -> p2 -> out*mask  (512 blocks,
// MT=16, 25KB LDS -> 3+ blocks/CU; 5 barriers total).
// ---------------------------------------------------------------------------
__global__ __launch_bounds__(256) void decode_kernel(
    const float* __restrict__ g1, const float* __restrict__ h,
    const float* __restrict__ wd, const float* __restrict__ bd,
    const float* __restrict__ wp1, const float* __restrict__ bp1,
    const float* __restrict__ wp2, const float* __restrict__ bp2,
    const float* __restrict__ wo, const float* __restrict__ bo,
    const float* __restrict__ mask, float* __restrict__ out) {
  __shared__ float bufA[16][AST];
  __shared__ float bufB[16][AST];
  __shared__ float bufH[16][AST];
  const int t = threadIdx.x;
  const int n0 = blockIdx.x * 16;
#pragma unroll
  for (int i = 0; i < 2; ++i) {  // stage g1 and h tiles (16x128 each)
    int lin = t + i * 256;
    int row = lin >> 5, k4 = (lin & 31) * 4;
    *(float4*)&bufA[row][k4] = *(const float4*)&g1[(size_t)(n0 + row) * 128 + k4];
    *(float4*)&bufH[row][k4] = *(const float4*)&h[(size_t)(n0 + row) * 128 + k4];
  }
  __syncthreads();
  layer_g<16, 128, 128, 128, true, true, 0>(bufA, nullptr, bufB, wd, bd, nullptr, nullptr, nullptr, n0, t);   // g2
  __syncthreads();
  layer_g<16, 256, 128, 128, true, true, 0>(bufB, bufH, bufA, wp1, bp1, nullptr, nullptr, nullptr, n0, t);    // p1
  __syncthreads();
  layer_g<16, 128, 128, 64, true, true, 0>(bufA, nullptr, bufB, wp2, bp2, nullptr, nullptr, nullptr, n0, t);  // p2
  __syncthreads();
  if (t < 128) {  // L4: out = (p2 @ wo.T + bo) * mask — F=8 per-thread dot
    const int row = t >> 3, c = t & 7;
    const float* wrow = wo + c * 64;
    float accv = 0.f;
#pragma unroll
    for (int k4 = 0; k4 < 16; ++k4) {
      float4 a = *(const float4*)&bufB[row][k4 * 4];
      float4 wv = *(const float4*)&wrow[k4 * 4];
      accv = fmaf(a.x, wv.x, accv);
      accv = fmaf(a.y, wv.y, accv);
      accv = fmaf(a.z, wv.z, accv);
      accv = fmaf(a.w, wv.w, accv);
    }
    const int node = n0 + row;
    out[(size_t)node * 8 + c] = (accv + bo[c]) * mask[node];
  }
}

extern "C" void kernel_launch(void* const* d_in, const int* in_sizes, int n_in,
                              void* d_out, int out_size, void* d_ws, size_t ws_size,
                              hipStream_t stream) {
  const float* x    = (const float*)d_in[0];
  const float* adj  = (const float*)d_in[1];
  const float* mask = (const float*)d_in[2];
  const float* w1   = (const float*)d_in[3];
  const float* b1   = (const float*)d_in[4];
  const float* w2   = (const float*)d_in[5];
  const float* b2   = (const float*)d_in[6];
  const float* wg   = (const float*)d_in[7];
  const float* bg   = (const float*)d_in[8];
  const float* wd   = (const float*)d_in[9];
  const float* bd   = (const float*)d_in[10];
  const float* wp1  = (const float*)d_in[11];
  const float* bp1  = (const float*)d_in[12];
  const float* wp2  = (const float*)d_in[13];
  const float* bp2  = (const float*)d_in[14];
  const float* wo   = (const float*)d_in[15];
  const float* bo   = (const float*)d_in[16];
  float* out = (float*)d_out;

  float* ws = (float*)d_ws;
  float* h    = ws; ws += (size_t)N_NODES * 128;
  float* msg  = ws; ws += (size_t)N_NODES * 128;
  float* g1   = ws; ws += (size_t)N_NODES * 128;
  int* cnt = (int*)ws; ws += N_NODES;
  int* nbr = (int*)ws;  // N_NODES * CAP ints

  scan_kernel<<<N_NODES / 4, 256, 0, stream>>>(adj, cnt, nbr);
  encode_kernel<<<N_NODES / 32, 256, 0, stream>>>(x, w1, b1, w2, b2, wg, cnt, h, msg);
  agg_kernel<<<N_NODES / 4, 256, 0, stream>>>(cnt, nbr, msg, bg, adj, g1);
  decode_kernel<<<N_NODES / 16, 256, 0, stream>>>(
      g1, h, wd, bd, wp1, bp1, wp2, bp2, wo, bo, mask, out);
}